// Round 1
// baseline (1149.684 us; speedup 1.0000x reference)
//
#include <hip/hip_runtime.h>

#define EMB   300
#define QLEN  256
#define DLEN  8192
#define KTOP  5

// ---------------- gather: out[r][e] = embeds[toks[r]][e] ----------------
__global__ void gather_rows(const float* __restrict__ embeds, const int* __restrict__ toks,
                            int rows, float* __restrict__ out) {
    long total = (long)rows * EMB;
    for (long idx = blockIdx.x * (long)blockDim.x + threadIdx.x; idx < total;
         idx += (long)gridDim.x * blockDim.x) {
        int r = (int)(idx / EMB);
        int e = (int)(idx - (long)r * EMB);
        out[idx] = embeds[(long)toks[r] * EMB + e];
    }
}

// ---------------- per-row inverse L2 norm ----------------
__global__ void row_invnorm(const float* __restrict__ X, int rows, float* __restrict__ inv) {
    int wave = (int)((blockIdx.x * (long)blockDim.x + threadIdx.x) >> 6);
    int lane = threadIdx.x & 63;
    if (wave >= rows) return;
    const float* row = X + (long)wave * EMB;
    float s = 0.f;
    for (int e = lane; e < EMB; e += 64) { float v = row[e]; s += v * v; }
    #pragma unroll
    for (int off = 32; off > 0; off >>= 1) s += __shfl_down(s, off, 64);
    if (lane == 0) inv[wave] = 1.0f / sqrtf(s);
}

// ---------------- tiled fp32 GEMM: C[M,N] = A[M,K] @ B[N,K]^T ----------------
// CONV==1: A is X (stride EMB); A[m][k] = X[m+shift+k/300][k%300] (0 if row>=Lrows)
//          epilogue: C = prelu(acc, *a_ptr) + X[m][n]
// CONV==0: plain A (stride K), plain store of acc.
template<int CONV>
__global__ void gemm_abt(const float* __restrict__ A, const float* __restrict__ B,
                         float* __restrict__ C, int M, int N, int K,
                         int shift, int Lrows, const float* __restrict__ a_ptr) {
    __shared__ float As[16][64];
    __shared__ float Bs[16][64];
    int tid = threadIdx.x;
    int tx = tid & 15, ty = tid >> 4;
    int m0 = blockIdx.y * 64, n0 = blockIdx.x * 64;
    float acc[4][4] = {};
    int ktiles = (K + 15) >> 4;
    for (int kt = 0; kt < ktiles; ++kt) {
        int k0 = kt << 4;
        #pragma unroll
        for (int i = 0; i < 4; ++i) {
            int idx = tid * 4 + i;
            int r = idx >> 4, kk = idx & 15;
            int k = k0 + kk;
            float v = 0.f;
            if (k < K) {
                if (CONV) {
                    int kh = k / EMB, e = k - kh * EMB;
                    int row = m0 + r + shift + kh;
                    if (row < Lrows) v = A[(long)row * EMB + e];
                } else {
                    int row = m0 + r;
                    if (row < M) v = A[(long)row * K + k];
                }
            }
            As[kk][r] = v;
        }
        #pragma unroll
        for (int i = 0; i < 4; ++i) {
            int idx = tid * 4 + i;
            int r = idx >> 4, kk = idx & 15;
            int k = k0 + kk;
            int col = n0 + r;
            float v = 0.f;
            if (k < K && col < N) v = B[(long)col * K + k];
            Bs[kk][r] = v;
        }
        __syncthreads();
        #pragma unroll
        for (int kk = 0; kk < 16; ++kk) {
            float a[4], b[4];
            #pragma unroll
            for (int i = 0; i < 4; ++i) a[i] = As[kk][ty * 4 + i];
            #pragma unroll
            for (int j = 0; j < 4; ++j) b[j] = Bs[kk][tx * 4 + j];
            #pragma unroll
            for (int i = 0; i < 4; ++i)
                #pragma unroll
                for (int j = 0; j < 4; ++j)
                    acc[i][j] += a[i] * b[j];
        }
        __syncthreads();
    }
    float alpha = CONV ? *a_ptr : 0.f;
    #pragma unroll
    for (int i = 0; i < 4; ++i) {
        int m = m0 + ty * 4 + i;
        if (m >= M) continue;
        #pragma unroll
        for (int j = 0; j < 4; ++j) {
            int n = n0 + tx * 4 + j;
            if (n >= N) continue;
            float v = acc[i][j];
            if (CONV) {
                v = v >= 0.f ? v : alpha * v;
                v += A[(long)m * EMB + n];
            }
            C[(long)m * N + n] = v;
        }
    }
}

// ---------------- top-5 pool per q-row -> feat[q*8 + c0] = max, [c0+1] = avg ----------------
// SRC 0: S is doc_sim [DLEN][QLEN], value = S[d][q]           (transposed read, no scaling)
// SRC 1: S is raw dots [QLEN][DLEN], value = S*qinv*dinv, masked by (qtok>1 && dtok>1)
// SRC 2: S is raw dots [QLEN][DLEN], value = S*qinv*dinv
#define INSERT5(arr, v)                                                          \
    if ((v) > arr[4]) {                                                          \
        arr[4] = (v);                                                            \
        if (arr[4] > arr[3]) { float t_ = arr[4]; arr[4] = arr[3]; arr[3] = t_; }\
        if (arr[3] > arr[2]) { float t_ = arr[3]; arr[3] = arr[2]; arr[2] = t_; }\
        if (arr[2] > arr[1]) { float t_ = arr[2]; arr[2] = arr[1]; arr[1] = t_; }\
        if (arr[1] > arr[0]) { float t_ = arr[1]; arr[1] = arr[0]; arr[0] = t_; }\
    }

template<int SRC>
__global__ void pool_topk(const float* __restrict__ S,
                          const float* __restrict__ qinv, const float* __restrict__ dinv,
                          const int* __restrict__ qtok, const int* __restrict__ dtok,
                          float* __restrict__ feat, int c0) {
    __shared__ float buf[256][KTOP];
    int q = blockIdx.x;
    int t = threadIdx.x;
    float top[KTOP];
    #pragma unroll
    for (int i = 0; i < KTOP; ++i) top[i] = -3.4e38f;
    float qs = (SRC != 0) ? qinv[q] : 1.f;
    bool qok = (SRC == 1) ? (qtok[q] > 1) : true;
    for (int d = t; d < DLEN; d += 256) {
        float v;
        if (SRC == 0) {
            v = S[(long)d * QLEN + q];
        } else {
            v = S[(long)q * DLEN + d] * qs * dinv[d];
            if (SRC == 1) { if (!qok || dtok[d] <= 1) v = 0.f; }
        }
        INSERT5(top, v);
    }
    #pragma unroll
    for (int i = 0; i < KTOP; ++i) buf[t][i] = top[i];
    __syncthreads();
    for (int stride = 128; stride >= 1; stride >>= 1) {
        if (t < stride) {
            float a0 = buf[t][0], a1 = buf[t][1], a2 = buf[t][2], a3 = buf[t][3], a4 = buf[t][4];
            float arr[KTOP] = {a0, a1, a2, a3, a4};
            #pragma unroll
            for (int r = 0; r < KTOP; ++r) {
                float v = buf[t + stride][r];
                INSERT5(arr, v);
            }
            #pragma unroll
            for (int i = 0; i < KTOP; ++i) buf[t][i] = arr[i];
        }
        __syncthreads();
    }
    if (t == 0) {
        float mx = buf[0][0];
        float sum = buf[0][0] + buf[0][1] + buf[0][2] + buf[0][3] + buf[0][4];
        feat[(long)q * 8 + c0] = mx;
        feat[(long)q * 8 + c0 + 1] = sum / (float)KTOP;
    }
}

// ---------------- final MLP + reduce + loss ----------------
__global__ void final_score(const float* __restrict__ feat1, const float* __restrict__ feat2,
                            const float* __restrict__ w1, const float* __restrict__ b1,
                            const float* __restrict__ w2, const float* __restrict__ b2,
                            const float* __restrict__ a1p, const float* __restrict__ a2p,
                            float* __restrict__ out) {
    __shared__ float s1buf[256], s2buf[256];
    int q = threadIdx.x;
    float a1 = *a1p, a2 = *a2p;
    float v[2];
    #pragma unroll
    for (int dsel = 0; dsel < 2; ++dsel) {
        const float* feat = dsel == 0 ? feat1 : feat2;
        float x[8];
        #pragma unroll
        for (int i = 0; i < 8; ++i) x[i] = feat[q * 8 + i];
        float lo[8];
        #pragma unroll
        for (int j = 0; j < 8; ++j) {
            float s = b1[j];
            #pragma unroll
            for (int i = 0; i < 8; ++i) s += x[i] * w1[j * 8 + i];
            lo[j] = s >= 0.f ? s : a1 * s;
        }
        float s2v = b2[0];
        #pragma unroll
        for (int j = 0; j < 8; ++j) s2v += lo[j] * w2[j];
        v[dsel] = s2v >= 0.f ? s2v : a2 * s2v;
    }
    s1buf[q] = v[0];
    s2buf[q] = v[1];
    __syncthreads();
    for (int st = 128; st >= 1; st >>= 1) {
        if (q < st) { s1buf[q] += s1buf[q + st]; s2buf[q] += s2buf[q + st]; }
        __syncthreads();
    }
    if (q == 0) {
        float d1 = s1buf[0] / (float)QLEN;
        float d2 = s2buf[0] / (float)QLEN;
        float loss1 = fmaxf(0.f, -(d1 - d2) + 0.9f);
        out[0] = loss1; out[1] = d1; out[2] = d2; out[3] = loss1; out[4] = 0.f;
    }
}

extern "C" void kernel_launch(void* const* d_in, const int* in_sizes, int n_in,
                              void* d_out, int out_size, void* d_ws, size_t ws_size,
                              hipStream_t stream) {
    const int*   doc1     = (const int*)d_in[0];
    const int*   doc2     = (const int*)d_in[1];
    const int*   question = (const int*)d_in[2];
    const float* doc1_sim = (const float*)d_in[3];
    const float* doc2_sim = (const float*)d_in[4];
    const float* embeds   = (const float*)d_in[5];
    const float* filt_bi  = (const float*)d_in[6];
    const float* filt_tri = (const float*)d_in[7];
    const float* a_bi     = (const float*)d_in[8];
    const float* a_tri    = (const float*)d_in[9];
    const float* w1       = (const float*)d_in[10];
    const float* b1       = (const float*)d_in[11];
    const float* w2       = (const float*)d_in[12];
    const float* b2       = (const float*)d_in[13];
    const float* a1       = (const float*)d_in[14];
    const float* a2       = (const float*)d_in[15];
    float* out = (float*)d_out;

    float* ws = (float*)d_ws;
    size_t off = 0;
    auto alloc = [&](size_t n) { float* p = ws + off; off += n; return p; };
    float* qe     = alloc((size_t)QLEN * EMB);
    float* d1e    = alloc((size_t)DLEN * EMB);
    float* d2e    = alloc((size_t)DLEN * EMB);
    float* q_bi   = alloc((size_t)QLEN * EMB);
    float* q_tri  = alloc((size_t)QLEN * EMB);
    float* d1_bi  = alloc((size_t)DLEN * EMB);
    float* d1_tri = alloc((size_t)DLEN * EMB);
    float* d2_bi  = alloc((size_t)DLEN * EMB);
    float* d2_tri = alloc((size_t)DLEN * EMB);
    float* sim    = alloc((size_t)QLEN * DLEN);
    float* qinv_e   = alloc(QLEN);
    float* qinv_bi  = alloc(QLEN);
    float* qinv_tri = alloc(QLEN);
    float* d1inv_e   = alloc(DLEN);
    float* d1inv_bi  = alloc(DLEN);
    float* d1inv_tri = alloc(DLEN);
    float* d2inv_e   = alloc(DLEN);
    float* d2inv_bi  = alloc(DLEN);
    float* d2inv_tri = alloc(DLEN);
    float* feat1 = alloc((size_t)QLEN * 8);
    float* feat2 = alloc((size_t)QLEN * 8);

    // --- gathers ---
    gather_rows<<<dim3((QLEN * EMB + 255) / 256), 256, 0, stream>>>(embeds, question, QLEN, qe);
    gather_rows<<<dim3(2048), 256, 0, stream>>>(embeds, doc1, DLEN, d1e);
    gather_rows<<<dim3(2048), 256, 0, stream>>>(embeds, doc2, DLEN, d2e);

    // --- conv GEMMs: Y = prelu(im2col(X) @ F^T) + X ---
    // bi: fs=2, K=600, shift=1 (rows r+1,r+2); tri: fs=3, K=900, shift=0 (rows r..r+2)
    gemm_abt<1><<<dim3(5, 4),   256, 0, stream>>>(qe,  filt_bi,  q_bi,   QLEN, EMB, 600, 1, QLEN, a_bi);
    gemm_abt<1><<<dim3(5, 4),   256, 0, stream>>>(qe,  filt_tri, q_tri,  QLEN, EMB, 900, 0, QLEN, a_tri);
    gemm_abt<1><<<dim3(5, 128), 256, 0, stream>>>(d1e, filt_bi,  d1_bi,  DLEN, EMB, 600, 1, DLEN, a_bi);
    gemm_abt<1><<<dim3(5, 128), 256, 0, stream>>>(d1e, filt_tri, d1_tri, DLEN, EMB, 900, 0, DLEN, a_tri);
    gemm_abt<1><<<dim3(5, 128), 256, 0, stream>>>(d2e, filt_bi,  d2_bi,  DLEN, EMB, 600, 1, DLEN, a_bi);
    gemm_abt<1><<<dim3(5, 128), 256, 0, stream>>>(d2e, filt_tri, d2_tri, DLEN, EMB, 900, 0, DLEN, a_tri);

    // --- row inverse norms ---
    row_invnorm<<<dim3(QLEN / 4), 256, 0, stream>>>(qe,    QLEN, qinv_e);
    row_invnorm<<<dim3(QLEN / 4), 256, 0, stream>>>(q_bi,  QLEN, qinv_bi);
    row_invnorm<<<dim3(QLEN / 4), 256, 0, stream>>>(q_tri, QLEN, qinv_tri);
    row_invnorm<<<dim3(DLEN / 4), 256, 0, stream>>>(d1e,    DLEN, d1inv_e);
    row_invnorm<<<dim3(DLEN / 4), 256, 0, stream>>>(d1_bi,  DLEN, d1inv_bi);
    row_invnorm<<<dim3(DLEN / 4), 256, 0, stream>>>(d1_tri, DLEN, d1inv_tri);
    row_invnorm<<<dim3(DLEN / 4), 256, 0, stream>>>(d2e,    DLEN, d2inv_e);
    row_invnorm<<<dim3(DLEN / 4), 256, 0, stream>>>(d2_bi,  DLEN, d2inv_bi);
    row_invnorm<<<dim3(DLEN / 4), 256, 0, stream>>>(d2_tri, DLEN, d2inv_tri);

    // --- oh pools (transposed reads of doc*_sim) ---
    pool_topk<0><<<dim3(QLEN), 256, 0, stream>>>(doc1_sim, nullptr, nullptr, nullptr, nullptr, feat1, 0);
    pool_topk<0><<<dim3(QLEN), 256, 0, stream>>>(doc2_sim, nullptr, nullptr, nullptr, nullptr, feat2, 0);

    // --- sim GEMM + pool, reusing one sim buffer (stream-serialized) ---
    dim3 sgrid(DLEN / 64, QLEN / 64);
    gemm_abt<0><<<sgrid, 256, 0, stream>>>(qe, d1e, sim, QLEN, DLEN, EMB, 0, 0, nullptr);
    pool_topk<1><<<dim3(QLEN), 256, 0, stream>>>(sim, qinv_e, d1inv_e, question, doc1, feat1, 2);
    gemm_abt<0><<<sgrid, 256, 0, stream>>>(qe, d2e, sim, QLEN, DLEN, EMB, 0, 0, nullptr);
    pool_topk<1><<<dim3(QLEN), 256, 0, stream>>>(sim, qinv_e, d2inv_e, question, doc2, feat2, 2);

    gemm_abt<0><<<sgrid, 256, 0, stream>>>(q_bi, d1_bi, sim, QLEN, DLEN, EMB, 0, 0, nullptr);
    pool_topk<2><<<dim3(QLEN), 256, 0, stream>>>(sim, qinv_bi, d1inv_bi, nullptr, nullptr, feat1, 4);
    gemm_abt<0><<<sgrid, 256, 0, stream>>>(q_bi, d2_bi, sim, QLEN, DLEN, EMB, 0, 0, nullptr);
    pool_topk<2><<<dim3(QLEN), 256, 0, stream>>>(sim, qinv_bi, d2inv_bi, nullptr, nullptr, feat2, 4);

    gemm_abt<0><<<sgrid, 256, 0, stream>>>(q_tri, d1_tri, sim, QLEN, DLEN, EMB, 0, 0, nullptr);
    pool_topk<2><<<dim3(QLEN), 256, 0, stream>>>(sim, qinv_tri, d1inv_tri, nullptr, nullptr, feat1, 6);
    gemm_abt<0><<<sgrid, 256, 0, stream>>>(q_tri, d2_tri, sim, QLEN, DLEN, EMB, 0, 0, nullptr);
    pool_topk<2><<<dim3(QLEN), 256, 0, stream>>>(sim, qinv_tri, d2inv_tri, nullptr, nullptr, feat2, 6);

    // --- final MLP + loss ---
    final_score<<<dim3(1), 256, 0, stream>>>(feat1, feat2, w1, b1, w2, b2, a1, a2, out);
}

// Round 2
// 226.223 us; speedup vs baseline: 5.0821x; 5.0821x over previous
//
#include <hip/hip_runtime.h>

#define EMB   300
#define QLEN  256
#define DLEN  8192
#define KTOP  5
#define STR   320      // bf16 row stride (elements)
#define STRB  640      // bf16 row stride (bytes)
#define KTT   10       // K tiles: 320/32

typedef __attribute__((ext_vector_type(8))) short short8v;
typedef __attribute__((ext_vector_type(4))) float f32x4;

__device__ inline float bf2f(short u) {
    return __uint_as_float(((unsigned int)(unsigned short)u) << 16);
}
__device__ inline short f2bf(float f) {
    unsigned int x = __float_as_uint(f);
    unsigned int r = x + 0x7fffu + ((x >> 16) & 1u);  // RNE
    return (short)(r >> 16);
}
__device__ inline void gload_lds16(const void* g, void* l) {
    __builtin_amdgcn_global_load_lds((const __attribute__((address_space(1))) void*)g,
                                     (__attribute__((address_space(3))) void*)l, 16, 0, 0);
}
// LDS swizzle involution on an 8KB [128 rows][64B] tile: XOR 16B-slot bits with row-pair bits
__device__ inline int swz(int a) { return a ^ (((a >> 7) & 7) << 4); }

// ---------------- gather + cast to bf16 (stride-320, cols>=300 stay zero) ----------------
__global__ void gather_cast(const float* __restrict__ embeds, const int* __restrict__ toks,
                            int rows, short* __restrict__ out) {
    long total = (long)rows * EMB;
    for (long idx = blockIdx.x * (long)blockDim.x + threadIdx.x; idx < total;
         idx += (long)gridDim.x * blockDim.x) {
        int r = (int)(idx / EMB);
        int e = (int)(idx - (long)r * EMB);
        out[(long)r * STR + e] = f2bf(embeds[(long)toks[r] * EMB + e]);
    }
}

// ---------------- filter cast: (O=300, fs, 300) f32 -> [fs][384][320] bf16 ----------------
__global__ void cast_filt(const float* __restrict__ filt, int fs, short* __restrict__ out) {
    long total = (long)EMB * fs * EMB;
    for (long idx = blockIdx.x * (long)blockDim.x + threadIdx.x; idx < total;
         idx += (long)gridDim.x * blockDim.x) {
        int o = (int)(idx / (fs * EMB));
        int rem = (int)(idx - (long)o * fs * EMB);
        int kh = rem / EMB, e = rem - kh * EMB;
        out[(long)kh * 384 * STR + (long)o * STR + e] = f2bf(filt[idx]);
    }
}

// ---------------- batched conv MFMA GEMM ----------------
// O[m][n] = bf16( prelu( sum_kh sum_e A[m+shift+kh][e] * F[kh][n][e], a ) + A[m][n] )
struct ConvSlice { const short* A; const short* F; short* O; const float* alpha; int M; int fs; int shift; };
struct ConvArgs { ConvSlice s[6]; };

__global__ __launch_bounds__(256) void conv_mfma(ConvArgs args) {
    ConvSlice sl;
    switch (blockIdx.z) {
        case 0: sl = args.s[0]; break; case 1: sl = args.s[1]; break;
        case 2: sl = args.s[2]; break; case 3: sl = args.s[3]; break;
        case 4: sl = args.s[4]; break; default: sl = args.s[5]; break;
    }
    int m0 = blockIdx.y * 128;
    if (m0 >= sl.M) return;
    int n0 = blockIdx.x * 128;

    __shared__ short As[4096];
    __shared__ short Bs[4096];
    int tid = threadIdx.x, lane = tid & 63, w = tid >> 6;
    int wr = w >> 1, wc = w & 1;

    int goff[2], ldsoff[2];
    #pragma unroll
    for (int i = 0; i < 2; ++i) {
        int phys = (2 * w + i) * 1024 + lane * 16;
        int lg = swz(phys);
        goff[i] = (lg >> 6) * STRB + ((lg >> 4) & 3) * 16;
        ldsoff[i] = (2 * w + i) * 1024;
    }

    f32x4 acc[4][4] = {};
    for (int kh = 0; kh < sl.fs; ++kh) {
        const char* Ab = (const char*)sl.A + (size_t)(m0 + sl.shift + kh) * STRB;
        const char* Bb = (const char*)sl.F + (size_t)kh * 384 * STRB + (size_t)n0 * STRB;
        for (int kt = 0; kt < KTT; ++kt) {
            int k0b = kt * 64;
            __syncthreads();
            #pragma unroll
            for (int i = 0; i < 2; ++i) {
                gload_lds16(Ab + k0b + goff[i], (char*)As + ldsoff[i]);
                gload_lds16(Bb + k0b + goff[i], (char*)Bs + ldsoff[i]);
            }
            __syncthreads();
            short8v a[4], b[4];
            #pragma unroll
            for (int f = 0; f < 4; ++f) {
                int ra = wr * 64 + f * 16 + (lane & 15);
                int la = ra * 64 + (lane >> 4) * 16;
                a[f] = *(const short8v*)((const char*)As + swz(la));
                int rb = wc * 64 + f * 16 + (lane & 15);
                int lb = rb * 64 + (lane >> 4) * 16;
                b[f] = *(const short8v*)((const char*)Bs + swz(lb));
            }
            #pragma unroll
            for (int mf = 0; mf < 4; ++mf)
                #pragma unroll
                for (int nf = 0; nf < 4; ++nf)
                    acc[mf][nf] = __builtin_amdgcn_mfma_f32_16x16x32_bf16(a[mf], b[nf], acc[mf][nf], 0, 0, 0);
        }
    }

    float al = *sl.alpha;
    #pragma unroll
    for (int mf = 0; mf < 4; ++mf) {
        int r0 = m0 + wr * 64 + mf * 16 + (lane >> 4) * 4;
        #pragma unroll
        for (int nf = 0; nf < 4; ++nf) {
            int c = n0 + wc * 64 + nf * 16 + (lane & 15);
            if (c < EMB) {
                #pragma unroll
                for (int j = 0; j < 4; ++j) {
                    int r = r0 + j;
                    if (r < sl.M) {
                        float v = acc[mf][nf][j];
                        v = v >= 0.f ? v : al * v;
                        v += bf2f(sl.A[(size_t)r * STR + c]);
                        sl.O[(size_t)r * STR + c] = f2bf(v);
                    }
                }
            }
        }
    }
}

// ---------------- batched sim MFMA GEMM: C f32[256][8192] = A[256][K=320] @ B[8192][320]^T --
struct SimSlice { const short* A; const short* B; float* C; };
struct SimArgs { SimSlice s[3]; };

__global__ __launch_bounds__(256) void sim_mfma(SimArgs args) {
    SimSlice sl;
    switch (blockIdx.z) {
        case 0: sl = args.s[0]; break; case 1: sl = args.s[1]; break;
        default: sl = args.s[2]; break;
    }
    int m0 = blockIdx.y * 128;
    int n0 = blockIdx.x * 128;

    __shared__ short As[4096];
    __shared__ short Bs[4096];
    int tid = threadIdx.x, lane = tid & 63, w = tid >> 6;
    int wr = w >> 1, wc = w & 1;

    int goff[2], ldsoff[2];
    #pragma unroll
    for (int i = 0; i < 2; ++i) {
        int phys = (2 * w + i) * 1024 + lane * 16;
        int lg = swz(phys);
        goff[i] = (lg >> 6) * STRB + ((lg >> 4) & 3) * 16;
        ldsoff[i] = (2 * w + i) * 1024;
    }

    const char* Ab = (const char*)sl.A + (size_t)m0 * STRB;
    const char* Bb = (const char*)sl.B + (size_t)n0 * STRB;
    f32x4 acc[4][4] = {};
    for (int kt = 0; kt < KTT; ++kt) {
        int k0b = kt * 64;
        __syncthreads();
        #pragma unroll
        for (int i = 0; i < 2; ++i) {
            gload_lds16(Ab + k0b + goff[i], (char*)As + ldsoff[i]);
            gload_lds16(Bb + k0b + goff[i], (char*)Bs + ldsoff[i]);
        }
        __syncthreads();
        short8v a[4], b[4];
        #pragma unroll
        for (int f = 0; f < 4; ++f) {
            int ra = wr * 64 + f * 16 + (lane & 15);
            int la = ra * 64 + (lane >> 4) * 16;
            a[f] = *(const short8v*)((const char*)As + swz(la));
            int rb = wc * 64 + f * 16 + (lane & 15);
            int lb = rb * 64 + (lane >> 4) * 16;
            b[f] = *(const short8v*)((const char*)Bs + swz(lb));
        }
        #pragma unroll
        for (int mf = 0; mf < 4; ++mf)
            #pragma unroll
            for (int nf = 0; nf < 4; ++nf)
                acc[mf][nf] = __builtin_amdgcn_mfma_f32_16x16x32_bf16(a[mf], b[nf], acc[mf][nf], 0, 0, 0);
    }

    #pragma unroll
    for (int mf = 0; mf < 4; ++mf) {
        int r0 = m0 + wr * 64 + mf * 16 + (lane >> 4) * 4;
        #pragma unroll
        for (int nf = 0; nf < 4; ++nf) {
            int c = n0 + wc * 64 + nf * 16 + (lane & 15);
            #pragma unroll
            for (int j = 0; j < 4; ++j)
                sl.C[(size_t)(r0 + j) * DLEN + c] = acc[mf][nf][j];
        }
    }
}

// ---------------- batched row inverse L2 norm from bf16 (stride 320, 300 valid) ------------
struct InvSlice { const short* X; float* inv; int rows; };
struct InvArgs { InvSlice s[9]; };

__global__ void inv_norms(InvArgs args) {
    InvSlice sl;
    switch (blockIdx.y) {
        case 0: sl = args.s[0]; break; case 1: sl = args.s[1]; break;
        case 2: sl = args.s[2]; break; case 3: sl = args.s[3]; break;
        case 4: sl = args.s[4]; break; case 5: sl = args.s[5]; break;
        case 6: sl = args.s[6]; break; case 7: sl = args.s[7]; break;
        default: sl = args.s[8]; break;
    }
    int row = blockIdx.x * 4 + (threadIdx.x >> 6);
    int lane = threadIdx.x & 63;
    if (row >= sl.rows) return;
    const short* p = sl.X + (size_t)row * STR;
    float s = 0.f;
    for (int e = lane; e < EMB; e += 64) { float v = bf2f(p[e]); s += v * v; }
    #pragma unroll
    for (int off = 32; off > 0; off >>= 1) s += __shfl_down(s, off, 64);
    if (lane == 0) sl.inv[row] = 1.0f / sqrtf(s);
}

// ---------------- top-5 insert ----------------
#define INSERT5(arr, v)                                                          \
    if ((v) > arr[4]) {                                                          \
        arr[4] = (v);                                                            \
        if (arr[4] > arr[3]) { float t_ = arr[4]; arr[4] = arr[3]; arr[3] = t_; }\
        if (arr[3] > arr[2]) { float t_ = arr[3]; arr[3] = arr[2]; arr[2] = t_; }\
        if (arr[2] > arr[1]) { float t_ = arr[2]; arr[2] = arr[1]; arr[1] = t_; }\
        if (arr[1] > arr[0]) { float t_ = arr[1]; arr[1] = arr[0]; arr[0] = t_; }\
    }

__device__ inline void topk_reduce_store(float top[KTOP], float (*buf)[KTOP], int t,
                                         float* feat, int q, int c0) {
    #pragma unroll
    for (int i = 0; i < KTOP; ++i) buf[t][i] = top[i];
    __syncthreads();
    for (int stride = 128; stride >= 1; stride >>= 1) {
        if (t < stride) {
            float arr[KTOP];
            #pragma unroll
            for (int i = 0; i < KTOP; ++i) arr[i] = buf[t][i];
            #pragma unroll
            for (int r = 0; r < KTOP; ++r) { float v = buf[t + stride][r]; INSERT5(arr, v); }
            #pragma unroll
            for (int i = 0; i < KTOP; ++i) buf[t][i] = arr[i];
        }
        __syncthreads();
    }
    if (t == 0) {
        float mx = buf[0][0];
        float sum = buf[0][0] + buf[0][1] + buf[0][2] + buf[0][3] + buf[0][4];
        feat[(long)q * 8 + c0] = mx;
        feat[(long)q * 8 + c0 + 1] = sum / (float)KTOP;
    }
}

// oh pool: S is doc_sim [DLEN][QLEN], value = S[d][q]
__global__ void pool_oh(const float* __restrict__ S, float* __restrict__ feat) {
    __shared__ float buf[256][KTOP];
    int q = blockIdx.x, t = threadIdx.x;
    float top[KTOP];
    #pragma unroll
    for (int i = 0; i < KTOP; ++i) top[i] = -3.4e38f;
    for (int d = t; d < DLEN; d += 256) {
        float v = S[(long)d * QLEN + q];
        INSERT5(top, v);
    }
    topk_reduce_store(top, buf, t, feat, q, 0);
}

// batched sim pools over 3 z-slices of the raw-dot buffer
struct PoolSlice { const float* qinv; const float* dinv; int mask; int c0; };
struct PoolArgs { PoolSlice s[3]; };

__global__ void pool_sim(const float* __restrict__ simbase, const int* __restrict__ qtok,
                         const int* __restrict__ dtok, float* __restrict__ feat, PoolArgs args) {
    PoolSlice sl;
    switch (blockIdx.y) {
        case 0: sl = args.s[0]; break; case 1: sl = args.s[1]; break;
        default: sl = args.s[2]; break;
    }
    __shared__ float buf[256][KTOP];
    int q = blockIdx.x, t = threadIdx.x;
    const float* S = simbase + (size_t)blockIdx.y * QLEN * DLEN + (size_t)q * DLEN;
    float qs = sl.qinv[q];
    bool qok = qtok[q] > 1;
    float top[KTOP];
    #pragma unroll
    for (int i = 0; i < KTOP; ++i) top[i] = -3.4e38f;
    for (int d = t; d < DLEN; d += 256) {
        float v = S[d] * qs * sl.dinv[d];
        if (sl.mask && (!qok || dtok[d] <= 1)) v = 0.f;
        INSERT5(top, v);
    }
    topk_reduce_store(top, buf, t, feat, q, sl.c0);
}

// ---------------- final MLP + reduce + loss ----------------
__global__ void final_score(const float* __restrict__ feat1, const float* __restrict__ feat2,
                            const float* __restrict__ w1, const float* __restrict__ b1,
                            const float* __restrict__ w2, const float* __restrict__ b2,
                            const float* __restrict__ a1p, const float* __restrict__ a2p,
                            float* __restrict__ out) {
    __shared__ float s1buf[256], s2buf[256];
    int q = threadIdx.x;
    float a1 = *a1p, a2 = *a2p;
    float v[2];
    #pragma unroll
    for (int dsel = 0; dsel < 2; ++dsel) {
        const float* feat = dsel == 0 ? feat1 : feat2;
        float x[8];
        #pragma unroll
        for (int i = 0; i < 8; ++i) x[i] = feat[q * 8 + i];
        float lo[8];
        #pragma unroll
        for (int j = 0; j < 8; ++j) {
            float s = b1[j];
            #pragma unroll
            for (int i = 0; i < 8; ++i) s += x[i] * w1[j * 8 + i];
            lo[j] = s >= 0.f ? s : a1 * s;
        }
        float s2v = b2[0];
        #pragma unroll
        for (int j = 0; j < 8; ++j) s2v += lo[j] * w2[j];
        v[dsel] = s2v >= 0.f ? s2v : a2 * s2v;
    }
    s1buf[q] = v[0];
    s2buf[q] = v[1];
    __syncthreads();
    for (int st = 128; st >= 1; st >>= 1) {
        if (q < st) { s1buf[q] += s1buf[q + st]; s2buf[q] += s2buf[q + st]; }
        __syncthreads();
    }
    if (q == 0) {
        float d1 = s1buf[0] / (float)QLEN;
        float d2 = s2buf[0] / (float)QLEN;
        float loss1 = fmaxf(0.f, -(d1 - d2) + 0.9f);
        out[0] = loss1; out[1] = d1; out[2] = d2; out[3] = loss1; out[4] = 0.f;
    }
}

extern "C" void kernel_launch(void* const* d_in, const int* in_sizes, int n_in,
                              void* d_out, int out_size, void* d_ws, size_t ws_size,
                              hipStream_t stream) {
    const int*   doc1     = (const int*)d_in[0];
    const int*   doc2     = (const int*)d_in[1];
    const int*   question = (const int*)d_in[2];
    const float* doc1_sim = (const float*)d_in[3];
    const float* doc2_sim = (const float*)d_in[4];
    const float* embeds   = (const float*)d_in[5];
    const float* filt_bi  = (const float*)d_in[6];
    const float* filt_tri = (const float*)d_in[7];
    const float* a_bi     = (const float*)d_in[8];
    const float* a_tri    = (const float*)d_in[9];
    const float* w1       = (const float*)d_in[10];
    const float* b1       = (const float*)d_in[11];
    const float* w2       = (const float*)d_in[12];
    const float* b2       = (const float*)d_in[13];
    const float* a1       = (const float*)d_in[14];
    const float* a2       = (const float*)d_in[15];
    float* out = (float*)d_out;

    float* ws = (float*)d_ws;
    size_t off = 0;
    auto allocf = [&](size_t n) { float* p = ws + off; off += n; return p; };
    const size_t SIMN = (size_t)QLEN * DLEN;
    float* simb  = allocf(SIMN * 3);
    float* feat1 = allocf(QLEN * 8);
    float* feat2 = allocf(QLEN * 8);
    float* qinv_e   = allocf(QLEN);
    float* qinv_bi  = allocf(QLEN);
    float* qinv_tri = allocf(QLEN);
    float* d1inv_e   = allocf(DLEN);
    float* d1inv_bi  = allocf(DLEN);
    float* d1inv_tri = allocf(DLEN);
    float* d2inv_e   = allocf(DLEN);
    float* d2inv_bi  = allocf(DLEN);
    float* d2inv_tri = allocf(DLEN);
    off = (off + 7) & ~(size_t)7;

    short* hb = (short*)(ws + off);
    size_t hoff = 0;
    auto alloch = [&](size_t n) { short* p = hb + hoff; hoff += n; return p; };
    const size_t QH = (size_t)(QLEN + 8) * STR;   // 264 rows
    const size_t DH = (size_t)(DLEN + 8) * STR;   // 8200 rows
    short* qe_h   = alloch(QH);
    short* qbi_h  = alloch(QH);
    short* qtri_h = alloch(QH);
    short* d1e_h   = alloch(DH);
    short* d1bi_h  = alloch(DH);
    short* d1tri_h = alloch(DH);
    short* d2e_h   = alloch(DH);
    short* d2bi_h  = alloch(DH);
    short* d2tri_h = alloch(DH);
    short* fbi_h  = alloch((size_t)2 * 384 * STR);
    short* ftri_h = alloch((size_t)3 * 384 * STR);

    // zero whole bf16 region (pad rows + pad cols must be 0)
    hipMemsetAsync(hb, 0, hoff * sizeof(short), stream);

    // gathers + filter casts
    gather_cast<<<dim3(300),  256, 0, stream>>>(embeds, question, QLEN, qe_h);
    gather_cast<<<dim3(2048), 256, 0, stream>>>(embeds, doc1, DLEN, d1e_h);
    gather_cast<<<dim3(2048), 256, 0, stream>>>(embeds, doc2, DLEN, d2e_h);
    cast_filt<<<dim3(512), 256, 0, stream>>>(filt_bi, 2, fbi_h);
    cast_filt<<<dim3(512), 256, 0, stream>>>(filt_tri, 3, ftri_h);

    // batched conv GEMMs (bi: fs=2 shift=1; tri: fs=3 shift=0)
    ConvArgs ca;
    ca.s[0] = { qe_h,  fbi_h,  qbi_h,  a_bi,  QLEN, 2, 1 };
    ca.s[1] = { qe_h,  ftri_h, qtri_h, a_tri, QLEN, 3, 0 };
    ca.s[2] = { d1e_h, fbi_h,  d1bi_h, a_bi,  DLEN, 2, 1 };
    ca.s[3] = { d1e_h, ftri_h, d1tri_h,a_tri, DLEN, 3, 0 };
    ca.s[4] = { d2e_h, fbi_h,  d2bi_h, a_bi,  DLEN, 2, 1 };
    ca.s[5] = { d2e_h, ftri_h, d2tri_h,a_tri, DLEN, 3, 0 };
    conv_mfma<<<dim3(3, 64, 6), 256, 0, stream>>>(ca);

    // batched inverse norms (from bf16 buffers)
    InvArgs ia;
    ia.s[0] = { qe_h,   qinv_e,   QLEN };
    ia.s[1] = { qbi_h,  qinv_bi,  QLEN };
    ia.s[2] = { qtri_h, qinv_tri, QLEN };
    ia.s[3] = { d1e_h,   d1inv_e,   DLEN };
    ia.s[4] = { d1bi_h,  d1inv_bi,  DLEN };
    ia.s[5] = { d1tri_h, d1inv_tri, DLEN };
    ia.s[6] = { d2e_h,   d2inv_e,   DLEN };
    ia.s[7] = { d2bi_h,  d2inv_bi,  DLEN };
    ia.s[8] = { d2tri_h, d2inv_tri, DLEN };
    inv_norms<<<dim3(2048, 9), 256, 0, stream>>>(ia);

    // oh pools (read doc_sim f32 directly)
    pool_oh<<<dim3(QLEN), 256, 0, stream>>>(doc1_sim, feat1);
    pool_oh<<<dim3(QLEN), 256, 0, stream>>>(doc2_sim, feat2);

    // d1 sims: raw dots then scaled/masked pools
    SimArgs sa1;
    sa1.s[0] = { qe_h,   d1e_h,   simb };
    sa1.s[1] = { qbi_h,  d1bi_h,  simb + SIMN };
    sa1.s[2] = { qtri_h, d1tri_h, simb + 2 * SIMN };
    sim_mfma<<<dim3(64, 2, 3), 256, 0, stream>>>(sa1);
    PoolArgs pa1;
    pa1.s[0] = { qinv_e,   d1inv_e,   1, 2 };
    pa1.s[1] = { qinv_bi,  d1inv_bi,  0, 4 };
    pa1.s[2] = { qinv_tri, d1inv_tri, 0, 6 };
    pool_sim<<<dim3(QLEN, 3), 256, 0, stream>>>(simb, question, doc1, feat1, pa1);

    // d2 sims
    SimArgs sa2;
    sa2.s[0] = { qe_h,   d2e_h,   simb };
    sa2.s[1] = { qbi_h,  d2bi_h,  simb + SIMN };
    sa2.s[2] = { qtri_h, d2tri_h, simb + 2 * SIMN };
    sim_mfma<<<dim3(64, 2, 3), 256, 0, stream>>>(sa2);
    PoolArgs pa2;
    pa2.s[0] = { qinv_e,   d2inv_e,   1, 2 };
    pa2.s[1] = { qinv_bi,  d2inv_bi,  0, 4 };
    pa2.s[2] = { qinv_tri, d2inv_tri, 0, 6 };
    pool_sim<<<dim3(QLEN, 3), 256, 0, stream>>>(simb, question, doc2, feat2, pa2);

    final_score<<<dim3(1), 256, 0, stream>>>(feat1, feat2, w1, b1, w2, b2, a1, a2, out);
}

// Round 3
// 187.357 us; speedup vs baseline: 6.1363x; 1.2074x over previous
//
#include <hip/hip_runtime.h>

#define EMB   300
#define QLEN  256
#define DLEN  8192
#define KTOP  5
#define STR   320      // bf16 row stride (elements)
#define STRB  640      // bf16 row stride (bytes)
#define KTT   10       // K tiles per kh: 320/32

typedef __attribute__((ext_vector_type(8))) short short8v;
typedef __attribute__((ext_vector_type(4))) float f32x4;

__device__ inline float bf2f(short u) {
    return __uint_as_float(((unsigned int)(unsigned short)u) << 16);
}
__device__ inline short f2bf(float f) {
    unsigned int x = __float_as_uint(f);
    unsigned int r = x + 0x7fffu + ((x >> 16) & 1u);  // RNE
    return (short)(r >> 16);
}
__device__ inline void gload_lds16(const void* g, void* l) {
    __builtin_amdgcn_global_load_lds((const __attribute__((address_space(1))) void*)g,
                                     (__attribute__((address_space(3))) void*)l, 16, 0, 0);
}
// LDS swizzle involution on an 8KB [128 rows][64B] tile
__device__ inline int swz(int a) { return a ^ (((a >> 7) & 7) << 4); }

// ---------------- batched gather + cast, writes pads (no memset needed) ----------------
struct GatherArgs { const int* toks[3]; short* out[3]; int rows[3]; };

__global__ void gather_cast(const float* __restrict__ embeds, GatherArgs ga) {
    int s = blockIdx.y;
    const int* toks = ga.toks[s];
    short* out = ga.out[s];
    int rows = ga.rows[s];
    long total = (long)(rows + 8) * STR;
    for (long idx = blockIdx.x * (long)blockDim.x + threadIdx.x; idx < total;
         idx += (long)gridDim.x * blockDim.x) {
        int r = (int)(idx / STR);
        int e = (int)(idx - (long)r * STR);
        short v = 0;
        if (r < rows && e < EMB) v = f2bf(embeds[(long)toks[r] * EMB + e]);
        out[idx] = v;
    }
}

// ---------------- batched filter cast: (300,1,fs,300) f32 -> [fs][384][320] bf16 ----------
struct FiltArgs { const float* f[2]; short* out[2]; int fs[2]; };

__global__ void cast_filt(FiltArgs fa) {
    int s = blockIdx.y;
    const float* f = fa.f[s];
    short* out = fa.out[s];
    int fs = fa.fs[s];
    long total = (long)fs * 384 * STR;
    for (long idx = blockIdx.x * (long)blockDim.x + threadIdx.x; idx < total;
         idx += (long)gridDim.x * blockDim.x) {
        int kh = (int)(idx / (384 * STR));
        int rem = (int)(idx - (long)kh * 384 * STR);
        int o = rem / STR, e = rem - o * STR;
        short v = 0;
        if (o < EMB && e < EMB) v = f2bf(f[(long)o * fs * EMB + (long)kh * EMB + e]);
        out[idx] = v;
    }
}

// ---------------- batched conv MFMA GEMM (2-phase LDS double-buffer) ----------------
// O[m][n] = bf16( prelu( sum_kh sum_e A[m+shift+kh][e]*F[kh][n][e], a ) + A[m][n] ), pads->0
struct ConvSlice { const short* A; const short* F; short* O; const float* alpha; int M; int fs; int shift; };
struct ConvArgs { ConvSlice s[6]; };

__global__ __launch_bounds__(256) void conv_mfma(ConvArgs args) {
    ConvSlice sl;
    switch (blockIdx.z) {
        case 0: sl = args.s[0]; break; case 1: sl = args.s[1]; break;
        case 2: sl = args.s[2]; break; case 3: sl = args.s[3]; break;
        case 4: sl = args.s[4]; break; default: sl = args.s[5]; break;
    }
    int m0 = blockIdx.y * 128;
    if (m0 >= sl.M) return;
    int n0 = blockIdx.x * 128;

    __shared__ short As[2][4096];
    __shared__ short Bs[2][4096];
    int tid = threadIdx.x, lane = tid & 63, w = tid >> 6;
    int wr = w >> 1, wc = w & 1;

    int goff[2], ldsoff[2];
    #pragma unroll
    for (int i = 0; i < 2; ++i) {
        int phys = (2 * w + i) * 1024 + lane * 16;
        int lg = swz(phys);
        goff[i] = (lg >> 6) * STRB + ((lg >> 4) & 3) * 16;
        ldsoff[i] = (2 * w + i) * 1024;
    }

    const char* Abase = (const char*)sl.A + (size_t)(m0 + sl.shift) * STRB;
    const char* Bbase = (const char*)sl.F + (size_t)n0 * STRB;
    int nt = sl.fs * KTT;

    auto stage = [&](int tg, int buf) {
        int kh = tg / KTT;
        int kt = tg - kh * KTT;
        const char* Ab = Abase + (size_t)kh * STRB;
        const char* Bb = Bbase + (size_t)kh * (384 * STRB);
        int k0b = kt * 64;
        gload_lds16(Ab + k0b + goff[0], (char*)As[buf] + ldsoff[0]);
        gload_lds16(Ab + k0b + goff[1], (char*)As[buf] + ldsoff[1]);
        gload_lds16(Bb + k0b + goff[0], (char*)Bs[buf] + ldsoff[0]);
        gload_lds16(Bb + k0b + goff[1], (char*)Bs[buf] + ldsoff[1]);
    };

    f32x4 acc[4][4] = {};
    stage(0, 0);
    __syncthreads();
    int cur = 0;
    for (int tg = 0; tg < nt; ++tg) {
        if (tg + 1 < nt) stage(tg + 1, cur ^ 1);
        short8v a[4], b[4];
        #pragma unroll
        for (int f = 0; f < 4; ++f) {
            int ra = wr * 64 + f * 16 + (lane & 15);
            int la = ra * 64 + (lane >> 4) * 16;
            a[f] = *(const short8v*)((const char*)As[cur] + swz(la));
            int rb = wc * 64 + f * 16 + (lane & 15);
            int lb = rb * 64 + (lane >> 4) * 16;
            b[f] = *(const short8v*)((const char*)Bs[cur] + swz(lb));
        }
        #pragma unroll
        for (int mf = 0; mf < 4; ++mf)
            #pragma unroll
            for (int nf = 0; nf < 4; ++nf)
                acc[mf][nf] = __builtin_amdgcn_mfma_f32_16x16x32_bf16(a[mf], b[nf], acc[mf][nf], 0, 0, 0);
        __syncthreads();
        cur ^= 1;
    }

    float al = *sl.alpha;
    #pragma unroll
    for (int mf = 0; mf < 4; ++mf) {
        int r0 = m0 + wr * 64 + mf * 16 + (lane >> 4) * 4;
        #pragma unroll
        for (int nf = 0; nf < 4; ++nf) {
            int c = n0 + wc * 64 + nf * 16 + (lane & 15);
            if (c < STR) {
                #pragma unroll
                for (int j = 0; j < 4; ++j) {
                    int r = r0 + j;
                    if (r < sl.M) {
                        short ov = 0;
                        if (c < EMB) {
                            float v = acc[mf][nf][j];
                            v = v >= 0.f ? v : al * v;
                            v += bf2f(sl.A[(size_t)r * STR + c]);
                            ov = f2bf(v);
                        }
                        sl.O[(size_t)r * STR + c] = ov;
                    }
                }
            }
        }
    }
}

// ------- batched sim MFMA GEMM (2-phase dbuf): C bf16[256][8192] = A[256][320] @ B[8192][320]^T
struct SimSlice { const short* A; const short* B; short* C; };
struct SimArgs { SimSlice s[6]; };

__global__ __launch_bounds__(256) void sim_mfma(SimArgs args) {
    SimSlice sl;
    switch (blockIdx.z) {
        case 0: sl = args.s[0]; break; case 1: sl = args.s[1]; break;
        case 2: sl = args.s[2]; break; case 3: sl = args.s[3]; break;
        case 4: sl = args.s[4]; break; default: sl = args.s[5]; break;
    }
    int m0 = blockIdx.y * 128;
    int n0 = blockIdx.x * 128;

    __shared__ short As[2][4096];
    __shared__ short Bs[2][4096];
    int tid = threadIdx.x, lane = tid & 63, w = tid >> 6;
    int wr = w >> 1, wc = w & 1;

    int goff[2], ldsoff[2];
    #pragma unroll
    for (int i = 0; i < 2; ++i) {
        int phys = (2 * w + i) * 1024 + lane * 16;
        int lg = swz(phys);
        goff[i] = (lg >> 6) * STRB + ((lg >> 4) & 3) * 16;
        ldsoff[i] = (2 * w + i) * 1024;
    }

    const char* Ab = (const char*)sl.A + (size_t)m0 * STRB;
    const char* Bb = (const char*)sl.B + (size_t)n0 * STRB;

    auto stage = [&](int kt, int buf) {
        int k0b = kt * 64;
        gload_lds16(Ab + k0b + goff[0], (char*)As[buf] + ldsoff[0]);
        gload_lds16(Ab + k0b + goff[1], (char*)As[buf] + ldsoff[1]);
        gload_lds16(Bb + k0b + goff[0], (char*)Bs[buf] + ldsoff[0]);
        gload_lds16(Bb + k0b + goff[1], (char*)Bs[buf] + ldsoff[1]);
    };

    f32x4 acc[4][4] = {};
    stage(0, 0);
    __syncthreads();
    int cur = 0;
    for (int kt = 0; kt < KTT; ++kt) {
        if (kt + 1 < KTT) stage(kt + 1, cur ^ 1);
        short8v a[4], b[4];
        #pragma unroll
        for (int f = 0; f < 4; ++f) {
            int ra = wr * 64 + f * 16 + (lane & 15);
            int la = ra * 64 + (lane >> 4) * 16;
            a[f] = *(const short8v*)((const char*)As[cur] + swz(la));
            int rb = wc * 64 + f * 16 + (lane & 15);
            int lb = rb * 64 + (lane >> 4) * 16;
            b[f] = *(const short8v*)((const char*)Bs[cur] + swz(lb));
        }
        #pragma unroll
        for (int mf = 0; mf < 4; ++mf)
            #pragma unroll
            for (int nf = 0; nf < 4; ++nf)
                acc[mf][nf] = __builtin_amdgcn_mfma_f32_16x16x32_bf16(a[mf], b[nf], acc[mf][nf], 0, 0, 0);
        __syncthreads();
        cur ^= 1;
    }

    #pragma unroll
    for (int mf = 0; mf < 4; ++mf) {
        int r0 = m0 + wr * 64 + mf * 16 + (lane >> 4) * 4;
        #pragma unroll
        for (int nf = 0; nf < 4; ++nf) {
            int c = n0 + wc * 64 + nf * 16 + (lane & 15);
            #pragma unroll
            for (int j = 0; j < 4; ++j)
                sl.C[(size_t)(r0 + j) * DLEN + c] = f2bf(acc[mf][nf][j]);
        }
    }
}

// ---------------- batched row inverse L2 norm from bf16 ----------------
struct InvSlice { const short* X; float* inv; int rows; };
struct InvArgs { InvSlice s[9]; };

__global__ void inv_norms(InvArgs args) {
    InvSlice sl;
    switch (blockIdx.y) {
        case 0: sl = args.s[0]; break; case 1: sl = args.s[1]; break;
        case 2: sl = args.s[2]; break; case 3: sl = args.s[3]; break;
        case 4: sl = args.s[4]; break; case 5: sl = args.s[5]; break;
        case 6: sl = args.s[6]; break; case 7: sl = args.s[7]; break;
        default: sl = args.s[8]; break;
    }
    int row = blockIdx.x * 4 + (threadIdx.x >> 6);
    int lane = threadIdx.x & 63;
    if (row >= sl.rows) return;
    const short* p = sl.X + (size_t)row * STR;
    float s = 0.f;
    for (int e = lane; e < EMB; e += 64) { float v = bf2f(p[e]); s += v * v; }
    #pragma unroll
    for (int off = 32; off > 0; off >>= 1) s += __shfl_down(s, off, 64);
    if (lane == 0) sl.inv[row] = 1.0f / sqrtf(s);
}

// ---------------- top-5 machinery ----------------
#define INSERT5(arr, v)                                                          \
    if ((v) > arr[4]) {                                                          \
        arr[4] = (v);                                                            \
        if (arr[4] > arr[3]) { float t_ = arr[4]; arr[4] = arr[3]; arr[3] = t_; }\
        if (arr[3] > arr[2]) { float t_ = arr[3]; arr[3] = arr[2]; arr[2] = t_; }\
        if (arr[2] > arr[1]) { float t_ = arr[2]; arr[2] = arr[1]; arr[1] = t_; }\
        if (arr[1] > arr[0]) { float t_ = arr[1]; arr[1] = arr[0]; arr[0] = t_; }\
    }

__device__ inline void topk_reduce_store(float top[KTOP], float (*buf)[KTOP], int t,
                                         float* feat, int q, int c0) {
    #pragma unroll
    for (int i = 0; i < KTOP; ++i) buf[t][i] = top[i];
    __syncthreads();
    for (int stride = 128; stride >= 1; stride >>= 1) {
        if (t < stride) {
            float arr[KTOP];
            #pragma unroll
            for (int i = 0; i < KTOP; ++i) arr[i] = buf[t][i];
            #pragma unroll
            for (int r = 0; r < KTOP; ++r) { float v = buf[t + stride][r]; INSERT5(arr, v); }
            #pragma unroll
            for (int i = 0; i < KTOP; ++i) buf[t][i] = arr[i];
        }
        __syncthreads();
    }
    if (t == 0) {
        float mx = buf[0][0];
        float sum = buf[0][0] + buf[0][1] + buf[0][2] + buf[0][3] + buf[0][4];
        feat[(long)q * 8 + c0] = mx;
        feat[(long)q * 8 + c0 + 1] = sum / (float)KTOP;
    }
}

// oh pool: S is doc_sim f32 [DLEN][QLEN], value = S[d][q]; y selects doc
__global__ void pool_oh(const float* __restrict__ S1, const float* __restrict__ S2,
                        float* __restrict__ feat1, float* __restrict__ feat2) {
    const float* S = blockIdx.y == 0 ? S1 : S2;
    float* feat = blockIdx.y == 0 ? feat1 : feat2;
    __shared__ float buf[256][KTOP];
    int q = blockIdx.x, t = threadIdx.x;
    float top[KTOP];
    #pragma unroll
    for (int i = 0; i < KTOP; ++i) top[i] = -3.4e38f;
    for (int d = t; d < DLEN; d += 256) {
        float v = S[(long)d * QLEN + q];
        INSERT5(top, v);
    }
    topk_reduce_store(top, buf, t, feat, q, 0);
}

// batched sim pools over 6 bf16 z-slices
struct PoolSlice { const float* qinv; const float* dinv; const int* dtok; float* feat; int mask; int c0; };
struct PoolArgs { PoolSlice s[6]; };

__global__ void pool_sim(const short* __restrict__ simbase, const int* __restrict__ qtok,
                         PoolArgs args) {
    PoolSlice sl;
    switch (blockIdx.y) {
        case 0: sl = args.s[0]; break; case 1: sl = args.s[1]; break;
        case 2: sl = args.s[2]; break; case 3: sl = args.s[3]; break;
        case 4: sl = args.s[4]; break; default: sl = args.s[5]; break;
    }
    __shared__ float buf[256][KTOP];
    int q = blockIdx.x, t = threadIdx.x;
    const short* S = simbase + (size_t)blockIdx.y * QLEN * DLEN + (size_t)q * DLEN;
    float qs = sl.qinv[q];
    bool qok = qtok[q] > 1;
    float top[KTOP];
    #pragma unroll
    for (int i = 0; i < KTOP; ++i) top[i] = -3.4e38f;
    for (int base = t * 8; base < DLEN; base += 2048) {
        short8v vv = *(const short8v*)(S + base);
        #pragma unroll
        for (int j = 0; j < 8; ++j) {
            float v = bf2f(vv[j]) * qs * sl.dinv[base + j];
            if (sl.mask && (!qok || sl.dtok[base + j] <= 1)) v = 0.f;
            INSERT5(top, v);
        }
    }
    topk_reduce_store(top, buf, t, sl.feat, q, sl.c0);
}

// ---------------- final MLP + reduce + loss ----------------
__global__ void final_score(const float* __restrict__ feat1, const float* __restrict__ feat2,
                            const float* __restrict__ w1, const float* __restrict__ b1,
                            const float* __restrict__ w2, const float* __restrict__ b2,
                            const float* __restrict__ a1p, const float* __restrict__ a2p,
                            float* __restrict__ out) {
    __shared__ float s1buf[256], s2buf[256];
    int q = threadIdx.x;
    float a1 = *a1p, a2 = *a2p;
    float v[2];
    #pragma unroll
    for (int dsel = 0; dsel < 2; ++dsel) {
        const float* feat = dsel == 0 ? feat1 : feat2;
        float x[8];
        #pragma unroll
        for (int i = 0; i < 8; ++i) x[i] = feat[q * 8 + i];
        float lo[8];
        #pragma unroll
        for (int j = 0; j < 8; ++j) {
            float s = b1[j];
            #pragma unroll
            for (int i = 0; i < 8; ++i) s += x[i] * w1[j * 8 + i];
            lo[j] = s >= 0.f ? s : a1 * s;
        }
        float s2v = b2[0];
        #pragma unroll
        for (int j = 0; j < 8; ++j) s2v += lo[j] * w2[j];
        v[dsel] = s2v >= 0.f ? s2v : a2 * s2v;
    }
    s1buf[q] = v[0];
    s2buf[q] = v[1];
    __syncthreads();
    for (int st = 128; st >= 1; st >>= 1) {
        if (q < st) { s1buf[q] += s1buf[q + st]; s2buf[q] += s2buf[q + st]; }
        __syncthreads();
    }
    if (q == 0) {
        float d1 = s1buf[0] / (float)QLEN;
        float d2 = s2buf[0] / (float)QLEN;
        float loss1 = fmaxf(0.f, -(d1 - d2) + 0.9f);
        out[0] = loss1; out[1] = d1; out[2] = d2; out[3] = loss1; out[4] = 0.f;
    }
}

extern "C" void kernel_launch(void* const* d_in, const int* in_sizes, int n_in,
                              void* d_out, int out_size, void* d_ws, size_t ws_size,
                              hipStream_t stream) {
    const int*   doc1     = (const int*)d_in[0];
    const int*   doc2     = (const int*)d_in[1];
    const int*   question = (const int*)d_in[2];
    const float* doc1_sim = (const float*)d_in[3];
    const float* doc2_sim = (const float*)d_in[4];
    const float* embeds   = (const float*)d_in[5];
    const float* filt_bi  = (const float*)d_in[6];
    const float* filt_tri = (const float*)d_in[7];
    const float* a_bi     = (const float*)d_in[8];
    const float* a_tri    = (const float*)d_in[9];
    const float* w1       = (const float*)d_in[10];
    const float* b1       = (const float*)d_in[11];
    const float* w2       = (const float*)d_in[12];
    const float* b2       = (const float*)d_in[13];
    const float* a1       = (const float*)d_in[14];
    const float* a2       = (const float*)d_in[15];
    float* out = (float*)d_out;

    float* ws = (float*)d_ws;
    size_t off = 0;
    auto allocf = [&](size_t n) { float* p = ws + off; off += n; return p; };
    float* feat1 = allocf(QLEN * 8);
    float* feat2 = allocf(QLEN * 8);
    float* qinv_e   = allocf(QLEN);
    float* qinv_bi  = allocf(QLEN);
    float* qinv_tri = allocf(QLEN);
    float* d1inv_e   = allocf(DLEN);
    float* d1inv_bi  = allocf(DLEN);
    float* d1inv_tri = allocf(DLEN);
    float* d2inv_e   = allocf(DLEN);
    float* d2inv_bi  = allocf(DLEN);
    float* d2inv_tri = allocf(DLEN);
    off = (off + 7) & ~(size_t)7;

    short* hb = (short*)(ws + off);
    size_t hoff = 0;
    auto alloch = [&](size_t n) { short* p = hb + hoff; hoff += n; return p; };
    const size_t QH = (size_t)(QLEN + 8) * STR;
    const size_t DH = (size_t)(DLEN + 8) * STR;
    const size_t SIMN = (size_t)QLEN * DLEN;
    short* qe_h   = alloch(QH);
    short* qbi_h  = alloch(QH);
    short* qtri_h = alloch(QH);
    short* d1e_h   = alloch(DH);
    short* d1bi_h  = alloch(DH);
    short* d1tri_h = alloch(DH);
    short* d2e_h   = alloch(DH);
    short* d2bi_h  = alloch(DH);
    short* d2tri_h = alloch(DH);
    short* fbi_h  = alloch((size_t)2 * 384 * STR);
    short* ftri_h = alloch((size_t)3 * 384 * STR);
    short* simb   = alloch(SIMN * 6);

    // gathers + filter casts (cover pads; no memset)
    GatherArgs ga;
    ga.toks[0] = question; ga.out[0] = qe_h;  ga.rows[0] = QLEN;
    ga.toks[1] = doc1;     ga.out[1] = d1e_h; ga.rows[1] = DLEN;
    ga.toks[2] = doc2;     ga.out[2] = d2e_h; ga.rows[2] = DLEN;
    gather_cast<<<dim3(2048, 3), 256, 0, stream>>>(embeds, ga);

    FiltArgs fa;
    fa.f[0] = filt_bi;  fa.out[0] = fbi_h;  fa.fs[0] = 2;
    fa.f[1] = filt_tri; fa.out[1] = ftri_h; fa.fs[1] = 3;
    cast_filt<<<dim3(512, 2), 256, 0, stream>>>(fa);

    // batched conv GEMMs (bi: fs=2 shift=1; tri: fs=3 shift=0)
    ConvArgs ca;
    ca.s[0] = { qe_h,  fbi_h,  qbi_h,  a_bi,  QLEN, 2, 1 };
    ca.s[1] = { qe_h,  ftri_h, qtri_h, a_tri, QLEN, 3, 0 };
    ca.s[2] = { d1e_h, fbi_h,  d1bi_h, a_bi,  DLEN, 2, 1 };
    ca.s[3] = { d1e_h, ftri_h, d1tri_h,a_tri, DLEN, 3, 0 };
    ca.s[4] = { d2e_h, fbi_h,  d2bi_h, a_bi,  DLEN, 2, 1 };
    ca.s[5] = { d2e_h, ftri_h, d2tri_h,a_tri, DLEN, 3, 0 };
    conv_mfma<<<dim3(3, 64, 6), 256, 0, stream>>>(ca);

    // batched inverse norms
    InvArgs ia;
    ia.s[0] = { qe_h,   qinv_e,   QLEN };
    ia.s[1] = { qbi_h,  qinv_bi,  QLEN };
    ia.s[2] = { qtri_h, qinv_tri, QLEN };
    ia.s[3] = { d1e_h,   d1inv_e,   DLEN };
    ia.s[4] = { d1bi_h,  d1inv_bi,  DLEN };
    ia.s[5] = { d1tri_h, d1inv_tri, DLEN };
    ia.s[6] = { d2e_h,   d2inv_e,   DLEN };
    ia.s[7] = { d2bi_h,  d2inv_bi,  DLEN };
    ia.s[8] = { d2tri_h, d2inv_tri, DLEN };
    inv_norms<<<dim3(2048, 9), 256, 0, stream>>>(ia);

    // oh pools (f32 inputs)
    pool_oh<<<dim3(QLEN, 2), 256, 0, stream>>>(doc1_sim, doc2_sim, feat1, feat2);

    // all 6 sim GEMMs in one launch (bf16 outputs)
    SimArgs sa;
    sa.s[0] = { qe_h,   d1e_h,   simb };
    sa.s[1] = { qbi_h,  d1bi_h,  simb + SIMN };
    sa.s[2] = { qtri_h, d1tri_h, simb + 2 * SIMN };
    sa.s[3] = { qe_h,   d2e_h,   simb + 3 * SIMN };
    sa.s[4] = { qbi_h,  d2bi_h,  simb + 4 * SIMN };
    sa.s[5] = { qtri_h, d2tri_h, simb + 5 * SIMN };
    sim_mfma<<<dim3(64, 2, 6), 256, 0, stream>>>(sa);

    // all 6 sim pools in one launch
    PoolArgs pa;
    pa.s[0] = { qinv_e,   d1inv_e,   doc1, feat1, 1, 2 };
    pa.s[1] = { qinv_bi,  d1inv_bi,  doc1, feat1, 0, 4 };
    pa.s[2] = { qinv_tri, d1inv_tri, doc1, feat1, 0, 6 };
    pa.s[3] = { qinv_e,   d2inv_e,   doc2, feat2, 1, 2 };
    pa.s[4] = { qinv_bi,  d2inv_bi,  doc2, feat2, 0, 4 };
    pa.s[5] = { qinv_tri, d2inv_tri, doc2, feat2, 0, 6 };
    pool_sim<<<dim3(QLEN, 6), 256, 0, stream>>>(simb, question, pa);

    final_score<<<dim3(1), 256, 0, stream>>>(feat1, feat2, w1, b1, w2, b2, a1, a2, out);
}